// Round 1
// baseline (125.293 us; speedup 1.0000x reference)
//
#include <hip/hip_runtime.h>

// CTC batch cost, B=64 T=1024 C=512 (blank=C-1) L=128, S=2L+1=257.
// Probability-domain forward algorithm with exact power-of-2 rescaling.
//   p_true = p_stored * 2^ksum * 256^-1024  (x256 folded into emissions)
//   loss   = -(log(p[255]+p[256]) + (ksum - 8192)*ln2)

#define EPSF 1e-7f
static constexpr int NB = 64;
static constexpr int NT = 1024;
static constexpr int NC = 512;
static constexpr int NL = 128;
static constexpr int CHUNK = 16;

// Kernel A: one wave per (b,t) row. rowsum reduce; optionally gather the
// 128 label probs (+blank) as e' = (y+eps) * 256/(rowsum + C*eps).
__global__ __launch_bounds__(256) void ctc_prep(const float* __restrict__ Y,
                                                const int* __restrict__ y_true,
                                                float* __restrict__ elab,
                                                float* __restrict__ eblank,
                                                int mode) {
    int gtid = blockIdx.x * 256 + threadIdx.x;
    int w = gtid >> 6;           // 0..B*T-1  (b*NT + t)
    int lane = gtid & 63;
    int b = w >> 10;
    const float* row = Y + (size_t)w * NC;

    float4 v0 = *reinterpret_cast<const float4*>(row + lane * 4);
    float4 v1 = *reinterpret_cast<const float4*>(row + (NC / 2) + lane * 4);
    float s = ((v0.x + v0.y) + (v0.z + v0.w)) + ((v1.x + v1.y) + (v1.z + v1.w));
#pragma unroll
    for (int d = 1; d < 64; d <<= 1) s += __shfl_xor(s, d);
    float inv = 256.0f / (s + NC * EPSF);

    if (mode == 1) {
        int2 lp = *reinterpret_cast<const int2*>(y_true + b * NL + lane * 2);
        float2 e;
        e.x = (row[lp.x] + EPSF) * inv;
        e.y = (row[lp.y] + EPSF) * inv;
        *reinterpret_cast<float2*>(elab + (size_t)w * NL + lane * 2) = e;
        if (lane == 0) eblank[w] = (row[NC - 1] + EPSF) * inv;
    } else {
        if (lane == 0) eblank[w] = inv;  // fallback: store inv only
    }
}

template <int MODE>
__device__ __forceinline__ void load_chunk(const float* __restrict__ A,
                                           const float* __restrict__ Bv,
                                           int b, int t0, int l, int lab0, int lab1,
                                           float2 (&buf)[CHUNK], float& bb, float& vv) {
    if constexpr (MODE == 1) {
        const float* base = A + ((size_t)b * NT + t0) * NL;
#pragma unroll
        for (int j = 0; j < CHUNK; j++)
            buf[j] = *reinterpret_cast<const float2*>(base + j * NL + 2 * l);
        bb = Bv[b * NT + t0 + (l & (CHUNK - 1))];
        vv = 0.0f;
    } else {
        const float* base = A + ((size_t)b * NT + t0) * NC;
#pragma unroll
        for (int j = 0; j < CHUNK; j++) {
            buf[j].x = base[(size_t)j * NC + lab0];
            buf[j].y = base[(size_t)j * NC + lab1];
        }
        int tt = t0 + (l & (CHUNK - 1));
        bb = A[((size_t)b * NT + tt) * NC + (NC - 1)];
        vv = Bv[b * NT + tt];
    }
}

// Kernel B: one wave per batch element. Lane l owns states 4l..4l+3
// (r0..r3); state 256 replicated in all lanes (pS). 1024 steps.
template <int MODE>
__global__ __launch_bounds__(64) void ctc_rec(const float* __restrict__ A,
                                              const float* __restrict__ Bv,
                                              const int* __restrict__ y_true,
                                              float* __restrict__ out) {
    const int b = blockIdx.x;
    const int l = threadIdx.x;
    const int* lab = y_true + b * NL;

    int lab_m1 = (l == 0) ? -1 : lab[2 * l - 1];
    int lab0 = lab[2 * l];
    int lab1 = lab[2 * l + 1];
    float sk0 = (lab0 != lab_m1) ? 1.0f : 0.0f;  // skip for state 4l+1
    float sk1 = (lab1 != lab0) ? 1.0f : 0.0f;    // skip for state 4l+3

    // p(-1): unit mass "before" state 0 -> step at t=0 reproduces alpha0.
    float p0 = (l == 0) ? 1.0f : 0.0f;
    float p1 = 0.0f, p2 = 0.0f, p3 = 0.0f, pS = 0.0f;
    int ksum = 0;

    float2 cur[CHUNK];
    float curb, curv;
    load_chunk<MODE>(A, Bv, b, 0, l, lab0, lab1, cur, curb, curv);

    for (int c = 0; c < NT / CHUNK; ++c) {
        float2 nxt[CHUNK];
        float nb = 0.0f, nv = 0.0f;
        if (c + 1 < NT / CHUNK)
            load_chunk<MODE>(A, Bv, b, (c + 1) * CHUNK, l, lab0, lab1, nxt, nb, nv);

#pragma unroll
        for (int j = 0; j < CHUNK; j++) {
            float eb, ex, ey;
            if constexpr (MODE == 1) {
                eb = __shfl(curb, j);
                ex = cur[j].x;
                ey = cur[j].y;
            } else {
                float iv = __shfl(curv, j);
                eb = (__shfl(curb, j) + EPSF) * iv;
                ex = (cur[j].x + EPSF) * iv;
                ey = (cur[j].y + EPSF) * iv;
            }
            float s3 = __shfl_up(p3, 1);      // lane l-1's r3 = state 4l-1
            if (l == 0) s3 = 0.0f;
            float bc = __shfl(p3, 63);        // state 255 (old)
            float n0 = (p0 + s3) * eb;                    // state 4l (blank)
            float n1 = (p1 + p0 + sk0 * s3) * ex;         // state 4l+1
            float n2 = (p2 + p1) * eb;                    // state 4l+2 (blank)
            float n3 = (p3 + p2 + sk1 * p1) * ey;         // state 4l+3
            pS = (pS + bc) * eb;                          // state 256 (blank)
            p0 = n0; p1 = n1; p2 = n2; p3 = n3;

            if ((j & 7) == 7) {  // exact power-of-2 rescale every 8 steps
                float m = fmaxf(fmaxf(fmaxf(p0, p1), fmaxf(p2, p3)), pS);
#pragma unroll
                for (int d = 1; d < 64; d <<= 1) m = fmaxf(m, __shfl_xor(m, d));
                int k;
                frexpf(m, &k);
                float sc = ldexpf(1.0f, -k);
                p0 *= sc; p1 *= sc; p2 *= sc; p3 *= sc; pS *= sc;
                ksum += k;
            }
        }

        if (c + 1 < NT / CHUNK) {
#pragma unroll
            for (int j = 0; j < CHUNK; j++) cur[j] = nxt[j];
            curb = nb;
            curv = nv;
        }
    }

    float p255 = __shfl(p3, 63);
    float tot = p255 + pS;
    float loss = -(logf(tot) + (float)(ksum - 8192) * 0.69314718055994531f);
    if (l == 0) out[b] = loss;
}

extern "C" void kernel_launch(void* const* d_in, const int* in_sizes, int n_in,
                              void* d_out, int out_size, void* d_ws, size_t ws_size,
                              hipStream_t stream) {
    const int* y_true = (const int*)d_in[0];
    const float* y_pred = (const float*)d_in[1];
    float* out = (float*)d_out;

    const size_t elab_bytes = (size_t)NB * NT * NL * sizeof(float);  // 32 MiB
    const size_t eb_bytes = (size_t)NB * NT * sizeof(float);         // 256 KiB

    if (ws_size >= elab_bytes + eb_bytes) {
        float* elab = (float*)d_ws;
        float* eblank = (float*)((char*)d_ws + elab_bytes);
        ctc_prep<<<NB * NT / 4, 256, 0, stream>>>(y_pred, y_true, elab, eblank, 1);
        ctc_rec<1><<<NB, 64, 0, stream>>>(elab, eblank, y_true, out);
    } else {
        // fallback: only inv(rowsum) fits in ws; gather from y_pred directly
        float* invb = (float*)d_ws;
        ctc_prep<<<NB * NT / 4, 256, 0, stream>>>(y_pred, y_true, nullptr, invb, 0);
        ctc_rec<0><<<NB, 64, 0, stream>>>(y_pred, invb, y_true, out);
    }
}

// Round 3
// 73.337 us; speedup vs baseline: 1.7085x; 1.7085x over previous
//
#include <hip/hip_runtime.h>

// CTC batch cost, B=64 T=1024 C=512 (blank=C-1) L=128, S=2L+1=257.
// Probability-domain forward algorithm with exact power-of-2 rescaling.
//   p_true = p_stored * 2^ksum * 256^-1024  (x256 folded into emissions)
//   loss   = -(log(p255+p256) + (ksum - 8192)*ln2)
// Lane l owns states 4l..4l+3; state 256 lives only in lane 63 (pS).
// No DS ops in the scan loop: neighbor exchange via DPP wave_shr:1 (0x138),
// rescale reduce via DPP row_shr/row_bcast (rocPRIM wave64 pattern).

#define EPSF 1e-7f
static constexpr int NB = 64;
static constexpr int NT = 1024;
static constexpr int NC = 512;
static constexpr int NL = 128;
static constexpr int CHUNK = 16;
static constexpr int NCH = NT / CHUNK;

// ---------------- kernel A: rowsum + gather ----------------
__global__ __launch_bounds__(256) void ctc_prep(const float* __restrict__ Y,
                                                const int* __restrict__ y_true,
                                                float* __restrict__ elab,
                                                float* __restrict__ eblank,
                                                int mode) {
    int gtid = blockIdx.x * 256 + threadIdx.x;
    int w = gtid >> 6;           // 0..B*T-1  (b*NT + t)
    int lane = gtid & 63;
    int b = w >> 10;
    const float* row = Y + (size_t)w * NC;

    float4 v0 = *reinterpret_cast<const float4*>(row + lane * 4);
    float4 v1 = *reinterpret_cast<const float4*>(row + (NC / 2) + lane * 4);
    float s = ((v0.x + v0.y) + (v0.z + v0.w)) + ((v1.x + v1.y) + (v1.z + v1.w));
#pragma unroll
    for (int d = 1; d < 64; d <<= 1) s += __shfl_xor(s, d);
    float inv = 256.0f / (s + NC * EPSF);

    if (mode == 1) {
        int2 lp = *reinterpret_cast<const int2*>(y_true + b * NL + lane * 2);
        float2 e;
        e.x = (row[lp.x] + EPSF) * inv;
        e.y = (row[lp.y] + EPSF) * inv;
        *reinterpret_cast<float2*>(elab + (size_t)w * NL + lane * 2) = e;
        if (lane == 0) eblank[w] = (row[NC - 1] + EPSF) * inv;
    } else {
        if (lane == 0) eblank[w] = inv;  // fallback: store inv(rowsum) only
    }
}

// ---------------- DPP helpers ----------------
__device__ __forceinline__ float dpp_wave_shr1(float x) {
    // lane l <- lane l-1, lane 0 <- 0   (DPP_CTRL 0x138 = WAVE_SHR1)
    return __int_as_float(__builtin_amdgcn_update_dpp(
        0, __float_as_int(x), 0x138, 0xF, 0xF, true));
}

__device__ __forceinline__ float dpp_wave_max(float m) {
    // values are >= 0, so zero-fill is harmless for max
#define DPPMAX_(ctrl)                                                     \
    m = fmaxf(m, __int_as_float(__builtin_amdgcn_update_dpp(              \
                     0, __float_as_int(m), ctrl, 0xF, 0xF, true)))
    DPPMAX_(0x111);  // row_shr:1
    DPPMAX_(0x112);  // row_shr:2
    DPPMAX_(0x114);  // row_shr:4
    DPPMAX_(0x118);  // row_shr:8
    DPPMAX_(0x142);  // row_bcast:15
    DPPMAX_(0x143);  // row_bcast:31
#undef DPPMAX_
    // lane 63 now holds the wave max; broadcast via readlane
    return __int_as_float(
        __builtin_amdgcn_readlane(__float_as_int(m), 63));
}

// ---------------- kernel B: the scan ----------------
template <int MODE>
__global__ __launch_bounds__(64) void ctc_rec(const float* __restrict__ A,
                                              const float* __restrict__ Bv,
                                              const int* __restrict__ y_true,
                                              float* __restrict__ out) {
    const int b = blockIdx.x;
    const int l = threadIdx.x;
    const int* lab = y_true + b * NL;

    int lab_m1 = (l == 0) ? -1 : lab[2 * l - 1];
    int lab0 = lab[2 * l];
    int lab1 = lab[2 * l + 1];
    float sk0 = (lab0 != lab_m1) ? 1.0f : 0.0f;  // skip into state 4l+1
    float sk1 = (lab1 != lab0) ? 1.0f : 0.0f;    // skip into state 4l+3

    // p(-1): unit mass "before" state 0 -> step at t=0 reproduces alpha0.
    float p0 = (l == 0) ? 1.0f : 0.0f;
    float p1 = 0.0f, p2 = 0.0f, p3 = 0.0f, pS = 0.0f;
    int ksum = 0;

    float2 L0[CHUNK], L1[CHUNK];
    float E0[CHUNK], E1[CHUNK];
    float I0[CHUNK], I1[CHUNK];

    auto load = [&](int c, float2(&L)[CHUNK], float(&E)[CHUNK],
                    float(&I)[CHUNK]) {
        if constexpr (MODE == 1) {
            const float* base = A + ((size_t)b * NT + c * CHUNK) * NL + 2 * l;
#pragma unroll
            for (int j = 0; j < CHUNK; j++)
                L[j] = *reinterpret_cast<const float2*>(base + (size_t)j * NL);
            const float* eb = Bv + b * NT + c * CHUNK;
#pragma unroll
            for (int q = 0; q < CHUNK / 4; q++)
                *reinterpret_cast<float4*>(&E[4 * q]) =
                    *reinterpret_cast<const float4*>(eb + 4 * q);
            (void)I;
        } else {
            const float* base = A + ((size_t)b * NT + c * CHUNK) * NC;
#pragma unroll
            for (int j = 0; j < CHUNK; j++) {
                L[j].x = base[(size_t)j * NC + lab0];
                L[j].y = base[(size_t)j * NC + lab1];
                E[j] = base[(size_t)j * NC + (NC - 1)];
            }
            const float* iv = Bv + b * NT + c * CHUNK;
#pragma unroll
            for (int q = 0; q < CHUNK / 4; q++)
                *reinterpret_cast<float4*>(&I[4 * q]) =
                    *reinterpret_cast<const float4*>(iv + 4 * q);
        }
    };

    auto process = [&](float2(&L)[CHUNK], float(&E)[CHUNK],
                       float(&I)[CHUNK]) {
#pragma unroll
        for (int j = 0; j < CHUNK; j++) {
            float eb, ex, ey;
            if constexpr (MODE == 1) {
                eb = E[j];
                ex = L[j].x;
                ey = L[j].y;
            } else {
                float iv = I[j];
                eb = (E[j] + EPSF) * iv;
                ex = (L[j].x + EPSF) * iv;
                ey = (L[j].y + EPSF) * iv;
            }
            float s3 = dpp_wave_shr1(p3);        // state 4l-1 (old)
            float n0 = (p0 + s3) * eb;           // state 4l   (blank)
            float n1 = (p1 + p0 + sk0 * s3) * ex;  // state 4l+1
            float n2 = (p2 + p1) * eb;           // state 4l+2 (blank)
            float n3 = (p3 + p2 + sk1 * p1) * ey;  // state 4l+3
            pS = (pS + p3) * eb;  // lane 63: state 256 <- {256, 255(old)}
            p0 = n0; p1 = n1; p2 = n2; p3 = n3;

            if ((j & 7) == 7) {  // exact power-of-2 rescale every 8 steps
                float m = fmaxf(fmaxf(p0, p1), fmaxf(p2, p3));
                m = fmaxf(m, (l == 63) ? pS : 0.0f);
                float mall = dpp_wave_max(m);
                int k;
                frexpf(mall, &k);
                float sc = ldexpf(1.0f, -k);
                p0 *= sc; p1 *= sc; p2 *= sc; p3 *= sc; pS *= sc;
                ksum += k;
            }
        }
    };

    load(0, L0, E0, I0);
    for (int c = 0; c < NCH; c += 2) {
        if (c + 1 < NCH) load(c + 1, L1, E1, I1);
        process(L0, E0, I0);
        if (c + 2 < NCH) load(c + 2, L0, E0, I0);
        process(L1, E1, I1);
    }

    if (l == 63) {
        float tot = p3 + pS;  // alpha_T[255] + alpha_T[256]
        out[b] = -(logf(tot) +
                   (float)(ksum - 8192) * 0.69314718055994531f);
    }
}

extern "C" void kernel_launch(void* const* d_in, const int* in_sizes, int n_in,
                              void* d_out, int out_size, void* d_ws, size_t ws_size,
                              hipStream_t stream) {
    const int* y_true = (const int*)d_in[0];
    const float* y_pred = (const float*)d_in[1];
    float* out = (float*)d_out;

    const size_t elab_bytes = (size_t)NB * NT * NL * sizeof(float);  // 32 MiB
    const size_t eb_bytes = (size_t)NB * NT * sizeof(float);         // 256 KiB

    if (ws_size >= elab_bytes + eb_bytes) {
        float* elab = (float*)d_ws;
        float* eblank = (float*)((char*)d_ws + elab_bytes);
        ctc_prep<<<NB * NT / 4, 256, 0, stream>>>(y_pred, y_true, elab, eblank, 1);
        ctc_rec<1><<<NB, 64, 0, stream>>>(elab, eblank, y_true, out);
    } else {
        // fallback: only inv(rowsum) fits in ws; gather from y_pred directly
        float* invb = (float*)d_ws;
        ctc_prep<<<NB * NT / 4, 256, 0, stream>>>(y_pred, y_true, nullptr, invb, 0);
        ctc_rec<0><<<NB, 64, 0, stream>>>(y_pred, invb, y_true, out);
    }
}

// Round 4
// 64.627 us; speedup vs baseline: 1.9387x; 1.1348x over previous
//
#include <hip/hip_runtime.h>

// CTC batch cost, B=64 T=1024 C=512 (blank=C-1) L=128, S=2L+1=257.
// Probability-domain forward algorithm with exact power-of-2 rescaling.
//   p_true = p_stored * 2^ksum * 256^-1024  (x256 folded into emissions)
//   loss   = -(log(p255+p256) + (ksum - 8192)*ln2)
// Lane l owns states 4l..4l+3; state 256 lives only in lane 63 (pS).
// No DS ops in the scan loop: neighbor exchange via DPP wave_shr:1 (0x138),
// rescale (every 16 steps) reduce via DPP row_shr/row_bcast, exponent
// extracted/applied with integer bit ops (no frexpf/ldexpf libcalls).
// Emissions staged as packed bf16 pairs (halves the ws traffic).

#define EPSF 1e-7f
static constexpr int NB = 64;
static constexpr int NT = 1024;
static constexpr int NC = 512;
static constexpr int NL = 128;
static constexpr int CHUNK = 32;
static constexpr int NCH = NT / CHUNK;

typedef unsigned int uint32;
typedef unsigned short ushort16;

__device__ __forceinline__ ushort16 rn_bf16(float x) {
    uint32 b = __float_as_uint(x);
    return (ushort16)((b + 0x7FFFu + ((b >> 16) & 1u)) >> 16);
}

// ---------------- kernel A: rowsum + gather, bf16-packed output ----------
__global__ __launch_bounds__(256) void ctc_prep(const float* __restrict__ Y,
                                                const int* __restrict__ y_true,
                                                uint32* __restrict__ elab,
                                                float* __restrict__ eblank,
                                                int mode) {
    int gtid = blockIdx.x * 256 + threadIdx.x;
    int w = gtid >> 6;           // 0..B*T-1  (b*NT + t)
    int lane = gtid & 63;
    int b = w >> 10;
    const float* row = Y + (size_t)w * NC;

    float4 v0 = *reinterpret_cast<const float4*>(row + lane * 4);
    float4 v1 = *reinterpret_cast<const float4*>(row + (NC / 2) + lane * 4);
    float s = ((v0.x + v0.y) + (v0.z + v0.w)) + ((v1.x + v1.y) + (v1.z + v1.w));
#pragma unroll
    for (int d = 1; d < 64; d <<= 1) s += __shfl_xor(s, d);
    float inv = 256.0f / (s + NC * EPSF);

    if (mode == 1) {
        int2 lp = *reinterpret_cast<const int2*>(y_true + b * NL + lane * 2);
        float ex = (row[lp.x] + EPSF) * inv;
        float ey = (row[lp.y] + EPSF) * inv;
        uint32 pk = (uint32)rn_bf16(ex) | ((uint32)rn_bf16(ey) << 16);
        elab[(size_t)w * (NL / 2) + lane] = pk;
        if (lane == 0) eblank[w] = (row[NC - 1] + EPSF) * inv;
    } else {
        if (lane == 0) eblank[w] = inv;  // fallback: store inv(rowsum) only
    }
}

// ---------------- DPP helpers ----------------
__device__ __forceinline__ float dpp_wave_shr1(float x) {
    // lane l <- lane l-1, lane 0 <- 0   (DPP_CTRL 0x138 = WAVE_SHR1)
    return __int_as_float(__builtin_amdgcn_update_dpp(
        0, __float_as_int(x), 0x138, 0xF, 0xF, true));
}

__device__ __forceinline__ float dpp_wave_max(float m) {
    // values are >= 0, so zero-fill is harmless for max
#define DPPMAX_(ctrl)                                                     \
    m = fmaxf(m, __int_as_float(__builtin_amdgcn_update_dpp(              \
                     0, __float_as_int(m), ctrl, 0xF, 0xF, true)))
    DPPMAX_(0x111);  // row_shr:1
    DPPMAX_(0x112);  // row_shr:2
    DPPMAX_(0x114);  // row_shr:4
    DPPMAX_(0x118);  // row_shr:8
    DPPMAX_(0x142);  // row_bcast:15
    DPPMAX_(0x143);  // row_bcast:31
#undef DPPMAX_
    return __int_as_float(
        __builtin_amdgcn_readlane(__float_as_int(m), 63));
}

// ---------------- kernel B: the scan (bf16-packed emissions) -------------
__global__ __launch_bounds__(64) void ctc_rec1(const uint32* __restrict__ A,
                                               const float* __restrict__ Bv,
                                               const int* __restrict__ y_true,
                                               float* __restrict__ out) {
    const int b = blockIdx.x;
    const int l = threadIdx.x;
    const int* lab = y_true + b * NL;

    int lab_m1 = (l == 0) ? -1 : lab[2 * l - 1];
    int lab0 = lab[2 * l];
    int lab1 = lab[2 * l + 1];
    float sk0 = (lab0 != lab_m1) ? 1.0f : 0.0f;  // skip into state 4l+1
    float sk1 = (lab1 != lab0) ? 1.0f : 0.0f;    // skip into state 4l+3

    float p0 = (l == 0) ? 1.0f : 0.0f;  // unit mass "before" state 0
    float p1 = 0.0f, p2 = 0.0f, p3 = 0.0f, pS = 0.0f;
    int ksum = 0;

    uint32 L0[CHUNK], L1[CHUNK];
    float E0[CHUNK], E1[CHUNK];

    auto load = [&](int c, uint32(&L)[CHUNK], float(&E)[CHUNK]) {
        const uint32* base = A + ((size_t)b * NT + c * CHUNK) * (NL / 2) + l;
#pragma unroll
        for (int j = 0; j < CHUNK; j++) L[j] = base[(size_t)j * (NL / 2)];
        const float* eb = Bv + b * NT + c * CHUNK;
#pragma unroll
        for (int q = 0; q < CHUNK / 4; q++)
            *reinterpret_cast<float4*>(&E[4 * q]) =
                *reinterpret_cast<const float4*>(eb + 4 * q);
    };

    auto process = [&](uint32(&L)[CHUNK], float(&E)[CHUNK]) {
#pragma unroll
        for (int j = 0; j < CHUNK; j++) {
            float eb = E[j];
            float ex = __uint_as_float(L[j] << 16);
            float ey = __uint_as_float(L[j] & 0xFFFF0000u);
            float s3 = dpp_wave_shr1(p3);          // state 4l-1 (old)
            float n0 = (p0 + s3) * eb;             // state 4l   (blank)
            float n1 = (p1 + p0 + sk0 * s3) * ex;  // state 4l+1
            float n2 = (p2 + p1) * eb;             // state 4l+2 (blank)
            float n3 = (p3 + p2 + sk1 * p1) * ey;  // state 4l+3
            pS = (pS + p3) * eb;  // lane 63: state 256 <- {256, 255(old)}
            p0 = n0; p1 = n1; p2 = n2; p3 = n3;

            if ((j & 15) == 15) {  // exact power-of-2 rescale every 16 steps
                float m = fmaxf(fmaxf(p0, p1), fmaxf(p2, p3));
                m = fmaxf(m, (l == 63) ? pS : 0.0f);
                float mall = fmaxf(dpp_wave_max(m), 1e-30f);
                int e = (int)(__float_as_uint(mall) >> 23) - 127;
                float sc = __uint_as_float((uint32)(127 - e) << 23);
                p0 *= sc; p1 *= sc; p2 *= sc; p3 *= sc; pS *= sc;
                ksum += e;
            }
        }
    };

    load(0, L0, E0);
    for (int c = 0; c < NCH; c += 2) {
        if (c + 1 < NCH) load(c + 1, L1, E1);
        process(L0, E0);
        if (c + 2 < NCH) load(c + 2, L0, E0);
        process(L1, E1);
    }

    if (l == 63) {
        float tot = p3 + pS;  // alpha_T[255] + alpha_T[256]
        out[b] = -(logf(tot) +
                   (float)(ksum - 8192) * 0.69314718055994531f);
    }
}

// ---------------- fallback scan (no gathered emissions in ws) ------------
__global__ __launch_bounds__(64) void ctc_rec0(const float* __restrict__ A,
                                               const float* __restrict__ Bv,
                                               const int* __restrict__ y_true,
                                               float* __restrict__ out) {
    const int b = blockIdx.x;
    const int l = threadIdx.x;
    const int* lab = y_true + b * NL;

    int lab_m1 = (l == 0) ? -1 : lab[2 * l - 1];
    int lab0 = lab[2 * l];
    int lab1 = lab[2 * l + 1];
    float sk0 = (lab0 != lab_m1) ? 1.0f : 0.0f;
    float sk1 = (lab1 != lab0) ? 1.0f : 0.0f;

    float p0 = (l == 0) ? 1.0f : 0.0f;
    float p1 = 0.0f, p2 = 0.0f, p3 = 0.0f, pS = 0.0f;
    int ksum = 0;

    for (int t = 0; t < NT; t++) {
        const float* base = A + ((size_t)b * NT + t) * NC;
        float iv = Bv[b * NT + t];
        float eb = (base[NC - 1] + EPSF) * iv;
        float ex = (base[lab0] + EPSF) * iv;
        float ey = (base[lab1] + EPSF) * iv;
        float s3 = dpp_wave_shr1(p3);
        float n0 = (p0 + s3) * eb;
        float n1 = (p1 + p0 + sk0 * s3) * ex;
        float n2 = (p2 + p1) * eb;
        float n3 = (p3 + p2 + sk1 * p1) * ey;
        pS = (pS + p3) * eb;
        p0 = n0; p1 = n1; p2 = n2; p3 = n3;
        if ((t & 15) == 15) {
            float m = fmaxf(fmaxf(p0, p1), fmaxf(p2, p3));
            m = fmaxf(m, (l == 63) ? pS : 0.0f);
            float mall = fmaxf(dpp_wave_max(m), 1e-30f);
            int e = (int)(__float_as_uint(mall) >> 23) - 127;
            float sc = __uint_as_float((uint32)(127 - e) << 23);
            p0 *= sc; p1 *= sc; p2 *= sc; p3 *= sc; pS *= sc;
            ksum += e;
        }
    }

    if (l == 63) {
        float tot = p3 + pS;
        out[b] = -(logf(tot) +
                   (float)(ksum - 8192) * 0.69314718055994531f);
    }
}

extern "C" void kernel_launch(void* const* d_in, const int* in_sizes, int n_in,
                              void* d_out, int out_size, void* d_ws, size_t ws_size,
                              hipStream_t stream) {
    const int* y_true = (const int*)d_in[0];
    const float* y_pred = (const float*)d_in[1];
    float* out = (float*)d_out;

    const size_t elab_bytes = (size_t)NB * NT * (NL / 2) * sizeof(uint32);  // 16 MiB
    const size_t eb_bytes = (size_t)NB * NT * sizeof(float);                // 256 KiB

    if (ws_size >= elab_bytes + eb_bytes) {
        uint32* elab = (uint32*)d_ws;
        float* eblank = (float*)((char*)d_ws + elab_bytes);
        ctc_prep<<<NB * NT / 4, 256, 0, stream>>>(y_pred, y_true, elab, eblank, 1);
        ctc_rec1<<<NB, 64, 0, stream>>>(elab, eblank, y_true, out);
    } else {
        float* invb = (float*)d_ws;
        ctc_prep<<<NB * NT / 4, 256, 0, stream>>>(y_pred, y_true, nullptr, invb, 0);
        ctc_rec0<<<NB, 64, 0, stream>>>(y_pred, invb, y_true, out);
    }
}